// Round 9
// baseline (10373.364 us; speedup 1.0000x reference)
//
#include <hip/hip_runtime.h>
#include <hip/hip_fp16.h>
#include <stdint.h>

// DagCellTorch R9: exact R6 structure (known-pass: absmax 9.77e-4, 4170us),
// with two zero-data-flow scheduling fixes:
//  - partA/partB split partials (16B lane stride, was 32B -> 5.1e7 conflicts)
//  - full unroll of stream16 (compiler hoists the 16 weight loads; R6's
//    "unroll 4" limited the scheduling window). NO manual prefetch rotation
//    (R7/R8's rotation is implicated in the 0.116 fallback failure), NO xproj.

#define T_STEPS 128
#define B_ROWS  512
#define NH      256
#define NPAIRS  9     // p=0:(wxc,wxh), p=1:(whc,whh), p=2..8: edges 0..6
#define KQ      64    // k-quads (4 k each)
#define BM      4
#define NBLK    (B_ROWS/BM)   // 128
#define NTHR    1024
#define SQ      4     // k-split
#define QPS     (KQ/SQ)       // 16 quads per thread per stream

__device__ __forceinline__ float sigmoidf_(float x){
  float e = __expf(-fabsf(x));
  float s = 1.f/(1.f+e);
  return x>=0.f ? s : 1.f-s;
}
__device__ __forceinline__ float tanhf_(float x){
  float e = __expf(-2.f*fabsf(x));
  float r = (1.f-e)/(1.f+e);
  return x>=0.f ? r : -r;
}
__device__ __forceinline__ unsigned short f2h(float f){
  return __half_as_ushort(__float2half(f));   // RNE
}
__device__ __forceinline__ uint32_t packh(float a, float b){
  return (uint32_t)f2h(a) | ((uint32_t)f2h(b) << 16);
}
__device__ __forceinline__ float fdot2_(uint32_t a, uint32_t b, float c){
  float d;
  asm("v_dot2_f32_f16 %0, %1, %2, %3" : "=v"(d) : "v"(a), "v"(b), "v"(c));
  return d;
}

// WQ[(((p*KQ + kq)*NH + n)*4 + c)]: c0=A k(4kq,4kq+1), c1=B same, c2=A k(+2,+3), c3=B same
__global__ void prep_weights(const float* __restrict__ wxc, const float* __restrict__ wxh,
                             const float* __restrict__ whc, const float* __restrict__ whh,
                             const float* __restrict__ Wc,  const float* __restrict__ Wh,
                             uint32_t* __restrict__ WQ){
  int idx = blockIdx.x*256 + threadIdx.x;
  if (idx >= NPAIRS*KQ*NH*4) return;
  int p   = idx >> 16;
  int rem = idx & 65535;
  int kq  = rem >> 10;
  int n   = (rem >> 2) & 255;
  int c   = rem & 3;
  int mat = c & 1;
  int k0  = 4*kq + 2*(c>>1);
  const float *A, *B;
  if (p == 0)      { A = wxc; B = wxh; }
  else if (p == 1) { A = whc; B = whh; }
  else             { A = Wc + (size_t)(p-2)*NH*NH; B = Wh + (size_t)(p-2)*NH*NH; }
  const float* M = mat ? B : A;
  WQ[idx] = packh(M[(size_t)n*NH + k0], M[(size_t)n*NH + k0 + 1]);
}

template<int ACT>  // 0 relu, 1 tanh, 2 sigmoid, 3 identity
__device__ __forceinline__ float actf(float v){
  if constexpr (ACT==0)      return fmaxf(v, 0.f);
  else if constexpr (ACT==1) return tanhf_(v);
  else if constexpr (ACT==2) return sigmoidf_(v);
  else                       return v;
}

// acc: 0,1=A k01/k23 r0; 2,3=B r0; 4..7 r1; 8..11 r2; 12..15 r3
__device__ __forceinline__ void stream16(const uint4* __restrict__ wp,
                                         const uint4 (* __restrict__ src)[2],
                                         int qb, float* acc){
  #pragma unroll
  for (int q = 0; q < QPS; ++q){
    const uint4 w  = wp[(size_t)q*NH];
    const uint4 ha = src[qb+q][0];   // r0:{k01,k23}, r1:{k01,k23}
    const uint4 hb = src[qb+q][1];   // r2, r3
    acc[0]  = fdot2_(w.x, ha.x, acc[0]);
    acc[1]  = fdot2_(w.z, ha.y, acc[1]);
    acc[2]  = fdot2_(w.y, ha.x, acc[2]);
    acc[3]  = fdot2_(w.w, ha.y, acc[3]);
    acc[4]  = fdot2_(w.x, ha.z, acc[4]);
    acc[5]  = fdot2_(w.z, ha.w, acc[5]);
    acc[6]  = fdot2_(w.y, ha.z, acc[6]);
    acc[7]  = fdot2_(w.w, ha.w, acc[7]);
    acc[8]  = fdot2_(w.x, hb.x, acc[8]);
    acc[9]  = fdot2_(w.z, hb.y, acc[9]);
    acc[10] = fdot2_(w.y, hb.x, acc[10]);
    acc[11] = fdot2_(w.w, hb.y, acc[11]);
    acc[12] = fdot2_(w.x, hb.z, acc[12]);
    acc[13] = fdot2_(w.z, hb.w, acc[13]);
    acc[14] = fdot2_(w.y, hb.z, acc[14]);
    acc[15] = fdot2_(w.w, hb.w, acc[15]);
  }
}

// pack 4 rows of hn (one col per lane) into hq; writers are (j&3)==0 lanes.
__device__ __forceinline__ void pack_hq(uint4 (*hq)[2], int j, const float* hn){
  uint4 v0, v1;
  float b1, b2, b3;
  b1=__shfl_down(hn[0],1); b2=__shfl_down(hn[0],2); b3=__shfl_down(hn[0],3);
  v0.x = packh(hn[0], b1); v0.y = packh(b2, b3);
  b1=__shfl_down(hn[1],1); b2=__shfl_down(hn[1],2); b3=__shfl_down(hn[1],3);
  v0.z = packh(hn[1], b1); v0.w = packh(b2, b3);
  b1=__shfl_down(hn[2],1); b2=__shfl_down(hn[2],2); b3=__shfl_down(hn[2],3);
  v1.x = packh(hn[2], b1); v1.y = packh(b2, b3);
  b1=__shfl_down(hn[3],1); b2=__shfl_down(hn[3],2); b3=__shfl_down(hn[3],3);
  v1.z = packh(hn[3], b1); v1.w = packh(b2, b3);
  if ((j & 3) == 0){ hq[j>>2][0] = v0; hq[j>>2][1] = v1; }
}

__global__ __launch_bounds__(NTHR) void dag_main(
    const float* __restrict__ x,    // (T,B,NH) f32
    const float* __restrict__ h0,   // (B,NH) f32
    const float* __restrict__ bxc,  // (NH)
    const float* __restrict__ bxh,  // (NH)
    const uint32_t* __restrict__ WQ,
    float* __restrict__ out)        // T*B*NH outputs then B*NH final hidden
{
  __shared__ uint4  hq[KQ][2];      // fp16 h quads: [kq][0]={r0k01,r0k23,r1k01,r1k23}
  __shared__ uint4  xq[KQ][2];      // fp16 x quads, same layout
  __shared__ float4 partA[SQ][NH];  // k-split partials, A (c-gate), rows 0..3
  __shared__ float4 partB[SQ][NH];  // k-split partials, B (h path), rows 0..3
  __shared__ float  red[4][BM];     // norm partials per finalize-wave

  const int tid = threadIdx.x;
  const int j   = tid & 255;
  const int s   = tid >> 8;
  const int qb  = s * QPS;
  const int r0  = blockIdx.x * BM;
  const uint4* WQ4   = (const uint4*)WQ;
  const uint4* wbase = WQ4 + (size_t)qb*NH + j;

  float hold[BM] = {0.f,0.f,0.f,0.f};
  float bc = 0.f, bh = 0.f;
  if (tid < 256){
    bc = bxc[j]; bh = bxh[j];
    #pragma unroll
    for (int r = 0; r < BM; ++r) hold[r] = h0[(size_t)(r0+r)*NH + j];
    pack_hq(hq, j, hold);
  }
  if (s == 3){
    #pragma unroll
    for (int i = 0; i < 2; ++i){
      int d  = j + i*256;
      int rr = d >> 7, kp = d & 127;
      const float2 xv = *(const float2*)&x[(size_t)(r0+rr)*NH + 2*kp];  // t=0
      int kq = kp>>1, hh = rr>>1, comp = ((rr&1)<<1) | (kp&1);
      ((uint32_t*)xq)[kq*8 + hh*4 + comp] = packh(xv.x, xv.y);
    }
  }
  __syncthreads();

  #define STORE_PART(acc) \
    partA[s][j] = make_float4(acc[0]+acc[1],  acc[4]+acc[5],  acc[8]+acc[9],   acc[12]+acc[13]); \
    partB[s][j] = make_float4(acc[2]+acc[3],  acc[6]+acc[7],  acc[10]+acc[11], acc[14]+acc[15]);

  #define SUM_PART(Av, Bv) \
    float Av[4] = {0,0,0,0}, Bv[4] = {0,0,0,0}; \
    _Pragma("unroll") \
    for (int ss = 0; ss < SQ; ++ss){ \
      float4 pa = partA[ss][j], pb = partB[ss][j]; \
      Av[0]+=pa.x; Av[1]+=pa.y; Av[2]+=pa.z; Av[3]+=pa.w; \
      Bv[0]+=pb.x; Bv[1]+=pb.y; Bv[2]+=pb.z; Bv[3]+=pb.w; \
    }

  for (int t = 0; t < T_STEPS; ++t){
    // ---- node 0: two streams (x via p=0, h via p=1) into one accumulator
    {
      float acc[16] = {};
      stream16(wbase,                    xq, qb, acc);
      stream16(wbase + (size_t)1*KQ*NH,  hq, qb, acc);
      STORE_PART(acc)
      __syncthreads();
      if (tid < 256){
        SUM_PART(Av, Bv)
        float hn[BM];
        #pragma unroll
        for (int r = 0; r < BM; ++r){
          float c = sigmoidf_(Av[r] + bc);
          float f = tanhf_(Bv[r] + bh);
          hn[r] = c*f + (1.f-c)*hold[r];
          hold[r] = hn[r];
        }
        pack_hq(hq, j, hn);
      }
      __syncthreads();
    }

    // ---- edges 0..5 (ACTS[1..6] = relu, tanh, sigmoid, identity, relu, tanh)
    #define EDGE_STAGE(P, ACT_)                                   \
    {                                                             \
      float acc[16] = {};                                         \
      stream16(wbase + (size_t)(P)*KQ*NH, hq, qb, acc);           \
      STORE_PART(acc)                                             \
      __syncthreads();                                            \
      if (tid < 256){                                             \
        SUM_PART(Av, Bv)                                          \
        float hn[BM];                                             \
        _Pragma("unroll")                                         \
        for (int r = 0; r < BM; ++r){                             \
          float c = sigmoidf_(Av[r]);                             \
          float f = actf<ACT_>(Bv[r]);                            \
          hn[r] = c*f + (1.f-c)*hold[r];                          \
          hold[r] = hn[r];                                        \
        }                                                         \
        pack_hq(hq, j, hn);                                       \
      }                                                           \
      __syncthreads();                                            \
    }

    EDGE_STAGE(2, 0)
    EDGE_STAGE(3, 1)
    EDGE_STAGE(4, 2)
    EDGE_STAGE(5, 3)
    EDGE_STAGE(6, 0)
    EDGE_STAGE(7, 1)
    #undef EDGE_STAGE

    // ---- edge 6 (identity, p=8) + norm clip + output write + xq prefetch
    {
      float acc[16] = {};
      stream16(wbase + (size_t)8*KQ*NH, hq, qb, acc);
      STORE_PART(acc)
      __syncthreads();
      float hn[BM];
      if (tid < 256){
        SUM_PART(Av, Bv)
        #pragma unroll
        for (int r = 0; r < BM; ++r){
          float c = sigmoidf_(Av[r]);
          hn[r] = c*Bv[r] + (1.f-c)*hold[r];
        }
        #pragma unroll
        for (int r = 0; r < BM; ++r){
          float pw = hn[r]*hn[r];
          #pragma unroll
          for (int off = 32; off; off >>= 1) pw += __shfl_xor(pw, off);
          if ((j & 63) == 0) red[j>>6][r] = pw;
        }
      }
      if (s == 3 && t + 1 < T_STEPS){
        #pragma unroll
        for (int i = 0; i < 2; ++i){
          int d  = j + i*256;
          int rr = d >> 7, kp = d & 127;
          const float2 xv = *(const float2*)&x[((size_t)(t+1)*B_ROWS + r0+rr)*NH + 2*kp];
          int kq = kp>>1, hh = rr>>1, comp = ((rr&1)<<1) | (kp&1);
          ((uint32_t*)xq)[kq*8 + hh*4 + comp] = packh(xv.x, xv.y);
        }
      }
      __syncthreads();
      if (tid < 256){
        #pragma unroll
        for (int r = 0; r < BM; ++r){
          float n2  = red[0][r] + red[1][r] + red[2][r] + red[3][r];
          float nrm = sqrtf(n2);
          float sc  = (nrm > 25.f) ? 25.f/nrm : 1.f;
          hn[r] *= sc;
          hold[r] = hn[r];
          out[(size_t)t*(B_ROWS*NH) + (size_t)(r0+r)*NH + j] = hn[r];
        }
        pack_hq(hq, j, hn);
      }
      __syncthreads();
    }
  }

  if (tid < 256){
    #pragma unroll
    for (int r = 0; r < BM; ++r)
      out[(size_t)T_STEPS*(B_ROWS*NH) + (size_t)(r0+r)*NH + j] = hold[r];
  }
  #undef STORE_PART
  #undef SUM_PART
}

extern "C" void kernel_launch(void* const* d_in, const int* in_sizes, int n_in,
                              void* d_out, int out_size, void* d_ws, size_t ws_size,
                              hipStream_t stream) {
  const float* x   = (const float*)d_in[0];
  const float* h0  = (const float*)d_in[1];
  const float* wxc = (const float*)d_in[2];
  const float* bxc = (const float*)d_in[3];
  const float* wxh = (const float*)d_in[4];
  const float* bxh = (const float*)d_in[5];
  const float* whc = (const float*)d_in[6];
  const float* whh = (const float*)d_in[7];
  const float* Wc  = (const float*)d_in[8];
  const float* Wh  = (const float*)d_in[9];
  uint32_t* WQ = (uint32_t*)d_ws;   // 9*64*256*4 dwords = 2.36 MB

  const int total = NPAIRS*KQ*NH*4;
  prep_weights<<<(total + 255)/256, 256, 0, stream>>>(wxc, wxh, whc, whh, Wc, Wh, WQ);
  dag_main<<<NBLK, NTHR, 0, stream>>>(x, h0, bxc, bxh, WQ, (float*)d_out);
}

// Round 10
// 8139.819 us; speedup vs baseline: 1.2744x; 1.2744x over previous
//
#include <hip/hip_runtime.h>
#include <hip/hip_fp16.h>
#include <stdint.h>

// DagCellTorch R10: MFMA recurrence. 32 blocks x 1024 threads (16 waves).
// Block owns BM=16 rows; wave ct owns cols [16ct,16ct+16), computes BOTH the
// c-gate and h matmuls (gating is wave-local). fp16 inputs, f32 MFMA accum
// (same numeric class as R6's dot2-f16 path, absmax 9.77e-4).
// Weights prepacked to exact B-fragment layout; h double-buffered in LDS.

#define T_STEPS 128
#define B_ROWS  512
#define NH      256
#define BM      16
#define NBLK    (B_ROWS/BM)   // 32
#define NTHR    1024
#define KSTEPS  8             // K=256 / 32

typedef _Float16 half8_t __attribute__((ext_vector_type(8)));
typedef float    f32x4_t __attribute__((ext_vector_type(4)));
union U4H8 { uint4 u; half8_t h; };

__device__ __forceinline__ float sigmoidf_(float x){
  float e = __expf(-fabsf(x));
  float s = 1.f/(1.f+e);
  return x>=0.f ? s : 1.f-s;
}
__device__ __forceinline__ float tanhf_(float x){
  float e = __expf(-2.f*fabsf(x));
  float r = (1.f-e)/(1.f+e);
  return x>=0.f ? r : -r;
}
__device__ __forceinline__ unsigned short f2h(float f){
  return __half_as_ushort(__float2half(f));   // RNE
}
__device__ __forceinline__ uint32_t packh(float a, float b){
  return (uint32_t)f2h(a) | ((uint32_t)f2h(b) << 16);
}

template<int ACT>  // 0 relu, 1 tanh, 2 sigmoid, 3 identity
__device__ __forceinline__ float actf(float v){
  if constexpr (ACT==0)      return fmaxf(v, 0.f);
  else if constexpr (ACT==1) return tanhf_(v);
  else if constexpr (ACT==2) return sigmoidf_(v);
  else                       return v;
}

// B-fragment weight pack. dword idx = ((((p*2+mat)*16+ct)*8+ks)*64+lane)*4+dw
// element: col = ct*16+(lane&15), k = ks*32+(lane>>4)*8+dw*2 -> packh(W[col][k], W[col][k+1])
__global__ void prep_weights(const float* __restrict__ wxc, const float* __restrict__ wxh,
                             const float* __restrict__ whc, const float* __restrict__ whh,
                             const float* __restrict__ Wc,  const float* __restrict__ Wh,
                             uint32_t* __restrict__ WM){
  int idx = blockIdx.x*256 + threadIdx.x;
  if (idx >= 9*2*16*8*64*4) return;
  int dw   = idx & 3;
  int lane = (idx >> 2) & 63;
  int ks   = (idx >> 8) & 7;
  int ct   = (idx >> 11) & 15;
  int mat  = (idx >> 15) & 1;
  int p    = idx >> 16;
  int col  = ct*16 + (lane & 15);
  int k    = ks*32 + (lane >> 4)*8 + dw*2;
  const float* M;
  if (p == 0)      M = mat ? wxh : wxc;
  else if (p == 1) M = mat ? whh : whc;
  else             M = (mat ? Wh : Wc) + (size_t)(p-2)*NH*NH;
  WM[idx] = packh(M[(size_t)col*NH + k], M[(size_t)col*NH + k + 1]);
}

// A = h-fragment from LDS (shared by both mats), B = weight fragments from L2.
__device__ __forceinline__ void stream_mfma(const uint4* __restrict__ wA,
                                            const uint4* __restrict__ wB,
                                            const uint4 (* __restrict__ hsrc)[4][16],
                                            int lane, f32x4_t& accA, f32x4_t& accB)
{
  const int m = lane & 15, g = lane >> 4;
  #pragma unroll
  for (int ks = 0; ks < KSTEPS; ++ks){
    U4H8 a, bA, bB;
    a.u  = hsrc[ks][g][m];
    bA.u = wA[ks*64 + lane];
    bB.u = wB[ks*64 + lane];
    accA = __builtin_amdgcn_mfma_f32_16x16x32_f16(a.h, bA.h, accA, 0, 0, 0);
    accB = __builtin_amdgcn_mfma_f32_16x16x32_f16(a.h, bB.h, accB, 0, 0, 0);
  }
}

// C/D frag (row=4g+r, col=ct*16+n) -> A-frag LDS layout [ks][g2][row] (k index = col).
__device__ __forceinline__ void write_hA(uint4 (* __restrict__ dst)[4][16],
                                         int ct, int lane, const float* hn)
{
  const int n = lane & 15, g = lane >> 4;
  float q0 = __shfl_xor(hn[0], 1);
  float q1 = __shfl_xor(hn[1], 1);
  float q2 = __shfl_xor(hn[2], 1);
  float q3 = __shfl_xor(hn[3], 1);
  if (!(lane & 1)){
    int ks  = ct >> 1;
    int g2  = ((ct & 1) << 1) | (n >> 3);
    int dwi = (n & 7) >> 1;
    ((uint32_t*)&dst[ks][g2][4*g + 0])[dwi] = packh(hn[0], q0);
    ((uint32_t*)&dst[ks][g2][4*g + 1])[dwi] = packh(hn[1], q1);
    ((uint32_t*)&dst[ks][g2][4*g + 2])[dwi] = packh(hn[2], q2);
    ((uint32_t*)&dst[ks][g2][4*g + 3])[dwi] = packh(hn[3], q3);
  }
}

__global__ __launch_bounds__(NTHR) void dag_mfma(
    const float* __restrict__ x,    // (T,B,NH) f32
    const float* __restrict__ h0,   // (B,NH) f32
    const float* __restrict__ bxc,  // (NH)
    const float* __restrict__ bxh,  // (NH)
    const uint32_t* __restrict__ WM,
    float* __restrict__ out)        // T*B*NH outputs then B*NH final hidden
{
  __shared__ uint4 hA[2][KSTEPS][4][16];   // 16 KB: fp16 h in A-frag layout, dbuf
  __shared__ uint4 xA[KSTEPS][4][16];      // 8 KB: fp16 x_t in A-frag layout
  __shared__ float redL[16][16];           // [wave ct][row] partial norm^2
  __shared__ float scaleL[16];             // per-row clip scale

  const int tid  = threadIdx.x;
  const int lane = tid & 63;
  const int ct   = tid >> 6;       // wave id = col-tile
  const int n    = lane & 15;
  const int g    = lane >> 4;
  const int col  = ct*16 + n;
  const int r0   = blockIdx.x * BM;
  const uint4* WM4 = (const uint4*)WM;

  const float bcv = bxc[col];
  const float bhv = bxh[col];

  float hold[4];
  #pragma unroll
  for (int r = 0; r < 4; ++r)
    hold[r] = h0[(size_t)(r0 + 4*g + r)*NH + col];
  write_hA(hA[0], ct, lane, hold);

  {  // xA for t=0: thread = (row m2 = tid>>6, k-quad = tid&63)
    float4 xv = ((const float4*)x)[((size_t)0*B_ROWS + r0 + (tid >> 6))*64 + (tid & 63)];
    int m2 = tid >> 6, k0 = (tid & 63)*4;
    int ks2 = k0 >> 5, g3 = (k0 >> 3) & 3, ih = (k0 & 7) >> 2;
    uint2 pk = make_uint2(packh(xv.x, xv.y), packh(xv.z, xv.w));
    ((uint2*)&xA[ks2][g3][m2])[ih] = pk;
  }
  __syncthreads();

  int buf = 0;
  for (int t = 0; t < T_STEPS; ++t){
    // ---- node 0: acc = bias + x·Wx^T + h·Wh^T ----
    {
      f32x4_t accA = {bcv, bcv, bcv, bcv};
      f32x4_t accB = {bhv, bhv, bhv, bhv};
      stream_mfma(WM4 + (( 0*16 + ct)*512), WM4 + (( 1*16 + ct)*512), xA,      lane, accA, accB);
      stream_mfma(WM4 + (( 2*16 + ct)*512), WM4 + (( 3*16 + ct)*512), hA[buf], lane, accA, accB);
      float hn[4];
      #pragma unroll
      for (int r = 0; r < 4; ++r){
        float c = sigmoidf_(accA[r]);
        float f = tanhf_(accB[r]);
        hn[r] = c*f + (1.f - c)*hold[r];
        hold[r] = hn[r];
      }
      write_hA(hA[buf^1], ct, lane, hn);
      __syncthreads();
      buf ^= 1;
    }

    // ---- edge 0 (p=2, relu) + x(t+1) prefetch ----
    {
      float4 xv;
      const bool doX = (t + 1 < T_STEPS);
      if (doX) xv = ((const float4*)x)[((size_t)(t+1)*B_ROWS + r0 + (tid >> 6))*64 + (tid & 63)];
      f32x4_t accA = {0.f,0.f,0.f,0.f}, accB = {0.f,0.f,0.f,0.f};
      stream_mfma(WM4 + ((4*16 + ct)*512), WM4 + ((5*16 + ct)*512), hA[buf], lane, accA, accB);
      float hn[4];
      #pragma unroll
      for (int r = 0; r < 4; ++r){
        float c = sigmoidf_(accA[r]);
        float f = fmaxf(accB[r], 0.f);
        hn[r] = c*f + (1.f - c)*hold[r];
        hold[r] = hn[r];
      }
      write_hA(hA[buf^1], ct, lane, hn);
      if (doX){
        int m2 = tid >> 6, k0 = (tid & 63)*4;
        int ks2 = k0 >> 5, g3 = (k0 >> 3) & 3, ih = (k0 & 7) >> 2;
        uint2 pk = make_uint2(packh(xv.x, xv.y), packh(xv.z, xv.w));
        ((uint2*)&xA[ks2][g3][m2])[ih] = pk;
      }
      __syncthreads();
      buf ^= 1;
    }

    // ---- edges 1..5 (p=3..7: tanh, sigmoid, identity, relu, tanh) ----
    #define EDGE(P, ACT_) { \
      f32x4_t accA = {0.f,0.f,0.f,0.f}, accB = {0.f,0.f,0.f,0.f}; \
      stream_mfma(WM4 + (((P)*2  )*16 + ct)*512 - 0 + 0, WM4 + ((((P)*2+1)*16 + ct)*512), hA[buf], lane, accA, accB); \
      float hn[4]; \
      _Pragma("unroll") \
      for (int r = 0; r < 4; ++r){ \
        float c = sigmoidf_(accA[r]); \
        float f = actf<ACT_>(accB[r]); \
        hn[r] = c*f + (1.f - c)*hold[r]; \
        hold[r] = hn[r]; \
      } \
      write_hA(hA[buf^1], ct, lane, hn); \
      __syncthreads(); \
      buf ^= 1; \
    }
    EDGE(3, 1)
    EDGE(4, 2)
    EDGE(5, 3)
    EDGE(6, 0)
    EDGE(7, 1)
    #undef EDGE

    // ---- edge 6 (p=8, identity) + norm clip + output ----
    {
      f32x4_t accA = {0.f,0.f,0.f,0.f}, accB = {0.f,0.f,0.f,0.f};
      stream_mfma(WM4 + ((16*16 + ct)*512), WM4 + ((17*16 + ct)*512), hA[buf], lane, accA, accB);
      float hn[4];
      #pragma unroll
      for (int r = 0; r < 4; ++r){
        float c = sigmoidf_(accA[r]);
        hn[r] = c*accB[r] + (1.f - c)*hold[r];
      }
      #pragma unroll
      for (int r = 0; r < 4; ++r){
        float v = hn[r]*hn[r];
        v += __shfl_xor(v, 1); v += __shfl_xor(v, 2);
        v += __shfl_xor(v, 4); v += __shfl_xor(v, 8);
        if (n == 0) redL[ct][4*g + r] = v;      // per-wave 16-col partial
      }
      __syncthreads();
      if (ct == 0){
        float tot = 0.f;
        #pragma unroll
        for (int c2 = 0; c2 < 16; ++c2) tot += redL[c2][n];
        float nrm = sqrtf(tot);
        scaleL[n] = (nrm > 25.f) ? 25.f/nrm : 1.f;   // 4 dup lanes, same value
      }
      __syncthreads();
      #pragma unroll
      for (int r = 0; r < 4; ++r){
        float sc = scaleL[4*g + r];
        hn[r] *= sc;
        hold[r] = hn[r];
        out[(size_t)t*(B_ROWS*NH) + (size_t)(r0 + 4*g + r)*NH + col] = hn[r];
      }
      write_hA(hA[buf^1], ct, lane, hn);
      __syncthreads();
      buf ^= 1;
    }
  }

  #pragma unroll
  for (int r = 0; r < 4; ++r)
    out[(size_t)T_STEPS*(B_ROWS*NH) + (size_t)(r0 + 4*g + r)*NH + col] = hold[r];
}

extern "C" void kernel_launch(void* const* d_in, const int* in_sizes, int n_in,
                              void* d_out, int out_size, void* d_ws, size_t ws_size,
                              hipStream_t stream) {
  const float* x   = (const float*)d_in[0];
  const float* h0  = (const float*)d_in[1];
  const float* wxc = (const float*)d_in[2];
  const float* bxc = (const float*)d_in[3];
  const float* wxh = (const float*)d_in[4];
  const float* bxh = (const float*)d_in[5];
  const float* whc = (const float*)d_in[6];
  const float* whh = (const float*)d_in[7];
  const float* Wc  = (const float*)d_in[8];
  const float* Wh  = (const float*)d_in[9];
  uint32_t* WM = (uint32_t*)d_ws;   // 589824 dwords = 2.36 MB

  const int total = 9*2*16*8*64*4;
  prep_weights<<<(total + 255)/256, 256, 0, stream>>>(wxc, wxh, whc, whh, Wc, Wh, WM);
  dag_mfma<<<NBLK, NTHR, 0, stream>>>(x, h0, bxc, bxh, WM, (float*)d_out);
}